// Round 1
// baseline (179.471 us; speedup 1.0000x reference)
//
#include <hip/hip_runtime.h>
#include <math.h>

// SVD++ scoring. One 64-lane wave per batch element.
// Wave layout: sub = lane>>4 (row group, 4 rows in flight), l16 = lane&15
// (column group: float4 at columns l16*4..l16*4+3 → 16 lanes cover a 256B row).
// dot(u + summed/norm, i) = u·i + (summed·i)/norm  → two scalar wave reductions.

#define WAVES_PER_BLOCK 4

__global__ __launch_bounds__(256) void svdpp_kernel(
    const int* __restrict__ user_ids,
    const int* __restrict__ item_ids,
    const int* __restrict__ offsets,
    const int* __restrict__ flat_implicit,
    const float* __restrict__ user_emb,
    const float* __restrict__ item_emb,
    const float* __restrict__ imp_emb,
    const float* __restrict__ user_bias,
    const float* __restrict__ item_bias,
    const float* __restrict__ global_bias,
    float* __restrict__ out,
    int B, int N)
{
    const int wave = threadIdx.x >> 6;
    const int lane = threadIdx.x & 63;
    const int b = blockIdx.x * WAVES_PER_BLOCK + wave;
    if (b >= B) return;

    const int sub = lane >> 4;   // 0..3: which row this lane helps load
    const int l16 = lane & 15;   // 0..15: which float4 of the row

    const int start = offsets[b];
    const int end   = (b + 1 < B) ? offsets[b + 1] : N;
    const int n     = end - start;

    const int user = user_ids[b];
    const int item = item_ids[b];

    // item-embedding fragment for this lane's 4 columns (broadcast across subs)
    const float4 i4 = ((const float4*)(item_emb + (size_t)item * 64))[l16];

    // ragged segment sum: 4 rows per wave-iteration, fully coalesced 256B rows
    float4 acc = make_float4(0.f, 0.f, 0.f, 0.f);
    for (int j = start + sub; j < end; j += 4) {
        const int idx = flat_implicit[j];   // 16 lanes same addr -> broadcast
        const float4 v = ((const float4*)(imp_emb + (size_t)idx * 64))[l16];
        acc.x += v.x; acc.y += v.y; acc.z += v.z; acc.w += v.w;
    }

    // partial of summed·i (full sum = reduce over all 64 lanes: subs × columns)
    float ds = acc.x * i4.x + acc.y * i4.y + acc.z * i4.z + acc.w * i4.w;

    // partial of u·i: one column per lane
    const float u_c = user_emb[(size_t)user * 64 + lane];
    const float i_c = item_emb[(size_t)item * 64 + lane];
    float dui = u_c * i_c;

    // wave-wide butterfly reduction of both scalars
    #pragma unroll
    for (int off = 32; off >= 1; off >>= 1) {
        ds  += __shfl_xor(ds,  off, 64);
        dui += __shfl_xor(dui, off, 64);
    }

    if (lane == 0) {
        const float norm = (n > 0) ? sqrtf((float)n) : 1.0f;
        out[b] = dui + ds / norm + user_bias[user] + item_bias[item]
               + global_bias[0];
    }
}

extern "C" void kernel_launch(void* const* d_in, const int* in_sizes, int n_in,
                              void* d_out, int out_size, void* d_ws, size_t ws_size,
                              hipStream_t stream) {
    const int*   user_ids      = (const int*)  d_in[0];
    const int*   item_ids      = (const int*)  d_in[1];
    const int*   offsets       = (const int*)  d_in[2];
    const int*   flat_implicit = (const int*)  d_in[3];
    const float* user_emb      = (const float*)d_in[4];
    const float* item_emb      = (const float*)d_in[5];
    const float* imp_emb       = (const float*)d_in[6];
    const float* user_bias     = (const float*)d_in[7];
    const float* item_bias     = (const float*)d_in[8];
    const float* global_bias   = (const float*)d_in[9];
    float* out = (float*)d_out;

    const int B = in_sizes[0];
    const int N = in_sizes[3];

    const int grid = (B + WAVES_PER_BLOCK - 1) / WAVES_PER_BLOCK;
    svdpp_kernel<<<grid, WAVES_PER_BLOCK * 64, 0, stream>>>(
        user_ids, item_ids, offsets, flat_implicit,
        user_emb, item_emb, imp_emb,
        user_bias, item_bias, global_bias,
        out, B, N);
}

// Round 2
// 146.887 us; speedup vs baseline: 1.2218x; 1.2218x over previous
//
#include <hip/hip_runtime.h>
#include <math.h>

// SVD++ scoring. One 64-lane wave per batch element.
// Wave layout: sub = lane>>4 (row group), l16 = lane&15 (float4 within the
// 256B row). dot(u + summed/norm, i) = u·i + (summed·i)/norm.
// R1: 4x unroll of the segment loop -> 4 idx loads + 4 row gathers in flight
// per wave (was 1+1 serial). Latency-bound fix; traffic unchanged.

#define WAVES_PER_BLOCK 4

__global__ __launch_bounds__(256) void svdpp_kernel(
    const int* __restrict__ user_ids,
    const int* __restrict__ item_ids,
    const int* __restrict__ offsets,
    const int* __restrict__ flat_implicit,
    const float* __restrict__ user_emb,
    const float* __restrict__ item_emb,
    const float* __restrict__ imp_emb,
    const float* __restrict__ user_bias,
    const float* __restrict__ item_bias,
    const float* __restrict__ global_bias,
    float* __restrict__ out,
    int B, int N)
{
    const int wave = threadIdx.x >> 6;
    const int lane = threadIdx.x & 63;
    const int b = blockIdx.x * WAVES_PER_BLOCK + wave;
    if (b >= B) return;

    const int sub = lane >> 4;   // 0..3: which row this lane helps load
    const int l16 = lane & 15;   // 0..15: which float4 of the row

    const int start = offsets[b];
    const int end   = (b + 1 < B) ? offsets[b + 1] : N;
    const int n     = end - start;

    const int user = user_ids[b];
    const int item = item_ids[b];

    // item-embedding fragment for this lane's 4 columns (broadcast across subs)
    const float4 i4 = ((const float4*)(item_emb + (size_t)item * 64))[l16];

    float4 acc = make_float4(0.f, 0.f, 0.f, 0.f);

    int j = start + sub;
    // main loop: 4 rows per sub-group per iteration (16 rows/wave/iter).
    // All 4 idx loads then all 4 gathers issue before any use -> 8 VMEM
    // ops in flight per wave.
    for (; j + 12 < end; j += 16) {
        const int idx0 = flat_implicit[j];
        const int idx1 = flat_implicit[j + 4];
        const int idx2 = flat_implicit[j + 8];
        const int idx3 = flat_implicit[j + 12];
        const float4 v0 = ((const float4*)(imp_emb + (size_t)idx0 * 64))[l16];
        const float4 v1 = ((const float4*)(imp_emb + (size_t)idx1 * 64))[l16];
        const float4 v2 = ((const float4*)(imp_emb + (size_t)idx2 * 64))[l16];
        const float4 v3 = ((const float4*)(imp_emb + (size_t)idx3 * 64))[l16];
        acc.x += v0.x + v1.x + v2.x + v3.x;
        acc.y += v0.y + v1.y + v2.y + v3.y;
        acc.z += v0.z + v1.z + v2.z + v3.z;
        acc.w += v0.w + v1.w + v2.w + v3.w;
    }
    // remainder
    for (; j < end; j += 4) {
        const int idx = flat_implicit[j];
        const float4 v = ((const float4*)(imp_emb + (size_t)idx * 64))[l16];
        acc.x += v.x; acc.y += v.y; acc.z += v.z; acc.w += v.w;
    }

    // partial of summed·i (full sum = reduce over all 64 lanes)
    float ds = acc.x * i4.x + acc.y * i4.y + acc.z * i4.z + acc.w * i4.w;

    // partial of u·i: one column per lane
    const float u_c = user_emb[(size_t)user * 64 + lane];
    const float i_c = item_emb[(size_t)item * 64 + lane];
    float dui = u_c * i_c;

    // wave-wide butterfly reduction of both scalars
    #pragma unroll
    for (int off = 32; off >= 1; off >>= 1) {
        ds  += __shfl_xor(ds,  off, 64);
        dui += __shfl_xor(dui, off, 64);
    }

    if (lane == 0) {
        const float norm = (n > 0) ? sqrtf((float)n) : 1.0f;
        out[b] = dui + ds / norm + user_bias[user] + item_bias[item]
               + global_bias[0];
    }
}

extern "C" void kernel_launch(void* const* d_in, const int* in_sizes, int n_in,
                              void* d_out, int out_size, void* d_ws, size_t ws_size,
                              hipStream_t stream) {
    const int*   user_ids      = (const int*)  d_in[0];
    const int*   item_ids      = (const int*)  d_in[1];
    const int*   offsets       = (const int*)  d_in[2];
    const int*   flat_implicit = (const int*)  d_in[3];
    const float* user_emb      = (const float*)d_in[4];
    const float* item_emb      = (const float*)d_in[5];
    const float* imp_emb       = (const float*)d_in[6];
    const float* user_bias     = (const float*)d_in[7];
    const float* item_bias     = (const float*)d_in[8];
    const float* global_bias   = (const float*)d_in[9];
    float* out = (float*)d_out;

    const int B = in_sizes[0];
    const int N = in_sizes[3];

    const int grid = (B + WAVES_PER_BLOCK - 1) / WAVES_PER_BLOCK;
    svdpp_kernel<<<grid, WAVES_PER_BLOCK * 64, 0, stream>>>(
        user_ids, item_ids, offsets, flat_implicit,
        user_emb, item_emb, imp_emb,
        user_bias, item_bias, global_bias,
        out, B, N);
}

// Round 3
// 146.714 us; speedup vs baseline: 1.2233x; 1.0012x over previous
//
#include <hip/hip_runtime.h>
#include <math.h>

// SVD++ scoring, R2: chunked-segment TLP.
// grid = (B/4, C): one 64-lane wave per (batch b, chunk c). Each wave sums
// rows [start + n*c/C, start + n*(c+1)/C) of b's implicit segment, dots with
// item_emb[item], and atomicAdds the scalar partial (pre-divided by norm)
// into out[b]. Chunk-0 wave also adds u·i + biases. out is zeroed by
// hipMemsetAsync before launch.
// Wave layout: sub = lane>>4 (4 rows in flight), l16 = lane&15 (float4 of the
// 256B row). dot(u + summed/norm, i) = u·i + (summed·i)/norm.

#define WAVES_PER_BLOCK 4
#define CHUNKS 2

__global__ __launch_bounds__(256) void svdpp_kernel(
    const int* __restrict__ user_ids,
    const int* __restrict__ item_ids,
    const int* __restrict__ offsets,
    const int* __restrict__ flat_implicit,
    const float* __restrict__ user_emb,
    const float* __restrict__ item_emb,
    const float* __restrict__ imp_emb,
    const float* __restrict__ user_bias,
    const float* __restrict__ item_bias,
    const float* __restrict__ global_bias,
    float* __restrict__ out,
    int B, int N)
{
    const int wave = threadIdx.x >> 6;
    const int lane = threadIdx.x & 63;
    const int b = blockIdx.x * WAVES_PER_BLOCK + wave;
    const int c = blockIdx.y;
    if (b >= B) return;

    const int sub = lane >> 4;   // 0..3: which row this lane helps load
    const int l16 = lane & 15;   // 0..15: which float4 of the row

    const int start = offsets[b];
    const int end   = (b + 1 < B) ? offsets[b + 1] : N;
    const int n     = end - start;

    // this wave's chunk of the segment
    const int cs = start + (int)(((long long)n * c) / CHUNKS);
    const int ce = start + (int)(((long long)n * (c + 1)) / CHUNKS);

    const int item = item_ids[b];

    // item-embedding fragment for this lane's 4 columns (broadcast across subs)
    const float4 i4 = ((const float4*)(item_emb + (size_t)item * 64))[l16];

    float4 acc = make_float4(0.f, 0.f, 0.f, 0.f);

    int j = cs + sub;
    // main: 16 rows/wave/iter — 4 idx loads + 4 row gathers in flight
    for (; j + 12 < ce; j += 16) {
        const int idx0 = flat_implicit[j];
        const int idx1 = flat_implicit[j + 4];
        const int idx2 = flat_implicit[j + 8];
        const int idx3 = flat_implicit[j + 12];
        const float4 v0 = ((const float4*)(imp_emb + (size_t)idx0 * 64))[l16];
        const float4 v1 = ((const float4*)(imp_emb + (size_t)idx1 * 64))[l16];
        const float4 v2 = ((const float4*)(imp_emb + (size_t)idx2 * 64))[l16];
        const float4 v3 = ((const float4*)(imp_emb + (size_t)idx3 * 64))[l16];
        acc.x += v0.x + v1.x + v2.x + v3.x;
        acc.y += v0.y + v1.y + v2.y + v3.y;
        acc.z += v0.z + v1.z + v2.z + v3.z;
        acc.w += v0.w + v1.w + v2.w + v3.w;
    }
    // middle: 8 rows
    if (j + 4 < ce) {
        const int idx0 = flat_implicit[j];
        const int idx1 = flat_implicit[j + 4];
        const float4 v0 = ((const float4*)(imp_emb + (size_t)idx0 * 64))[l16];
        const float4 v1 = ((const float4*)(imp_emb + (size_t)idx1 * 64))[l16];
        acc.x += v0.x + v1.x; acc.y += v0.y + v1.y;
        acc.z += v0.z + v1.z; acc.w += v0.w + v1.w;
        j += 8;
    }
    // remainder: 4 rows
    if (j < ce) {
        const int idx = flat_implicit[j];
        const float4 v = ((const float4*)(imp_emb + (size_t)idx * 64))[l16];
        acc.x += v.x; acc.y += v.y; acc.z += v.z; acc.w += v.w;
    }

    // partial of summed·i (reduce over all 64 lanes: subs × columns)
    float val = acc.x * i4.x + acc.y * i4.y + acc.z * i4.z + acc.w * i4.w;

    float dui = 0.f;
    if (c == 0) {
        const int user = user_ids[b];
        const float u_c = user_emb[(size_t)user * 64 + lane];
        const float i_c = item_emb[(size_t)item * 64 + lane];
        dui = u_c * i_c;
        // fold the lane-0-only bias terms in after the reduction
    }

    #pragma unroll
    for (int off = 32; off >= 1; off >>= 1) {
        val += __shfl_xor(val, off, 64);
        dui += __shfl_xor(dui, off, 64);
    }

    if (lane == 0) {
        const float norm = (n > 0) ? sqrtf((float)n) : 1.0f;
        float contrib = val / norm;
        if (c == 0) {
            const int user = user_ids[b];
            contrib += dui + user_bias[user] + item_bias[item] + global_bias[0];
        }
        atomicAdd(out + b, contrib);
    }
}

extern "C" void kernel_launch(void* const* d_in, const int* in_sizes, int n_in,
                              void* d_out, int out_size, void* d_ws, size_t ws_size,
                              hipStream_t stream) {
    const int*   user_ids      = (const int*)  d_in[0];
    const int*   item_ids      = (const int*)  d_in[1];
    const int*   offsets       = (const int*)  d_in[2];
    const int*   flat_implicit = (const int*)  d_in[3];
    const float* user_emb      = (const float*)d_in[4];
    const float* item_emb      = (const float*)d_in[5];
    const float* imp_emb       = (const float*)d_in[6];
    const float* user_bias     = (const float*)d_in[7];
    const float* item_bias     = (const float*)d_in[8];
    const float* global_bias   = (const float*)d_in[9];
    float* out = (float*)d_out;

    const int B = in_sizes[0];
    const int N = in_sizes[3];

    hipMemsetAsync(out, 0, (size_t)B * sizeof(float), stream);

    dim3 grid((B + WAVES_PER_BLOCK - 1) / WAVES_PER_BLOCK, CHUNKS);
    svdpp_kernel<<<grid, WAVES_PER_BLOCK * 64, 0, stream>>>(
        user_ids, item_ids, offsets, flat_implicit,
        user_emb, item_emb, imp_emb,
        user_bias, item_bias, global_bias,
        out, B, N);
}

// Round 4
// 143.485 us; speedup vs baseline: 1.2508x; 1.0225x over previous
//
#include <hip/hip_runtime.h>
#include <math.h>

// SVD++ scoring, R3: deep per-wave MLP.
// One 64-lane wave per batch element b. sub = lane>>4 (row group),
// l16 = lane&15 (float4 within the 256B row).
// Each iteration issues DEPTH=16 predicated idx loads then DEPTH row-gathers
// per sub-group (64 rows/wave, 16KB in flight) before any accumulation —
// latency-bound fix: R2 showed waves averaged only ~230B in flight.
// dot(u + summed/norm, i) = u·i + (summed·i)/norm -> scalar wave reductions.
// One wave owns out[b] -> plain store, no atomics/memset.

#define WAVES_PER_BLOCK 4
#define DEPTH 16

__global__ __launch_bounds__(256) void svdpp_kernel(
    const int* __restrict__ user_ids,
    const int* __restrict__ item_ids,
    const int* __restrict__ offsets,
    const int* __restrict__ flat_implicit,
    const float* __restrict__ user_emb,
    const float* __restrict__ item_emb,
    const float* __restrict__ imp_emb,
    const float* __restrict__ user_bias,
    const float* __restrict__ item_bias,
    const float* __restrict__ global_bias,
    float* __restrict__ out,
    int B, int N)
{
    const int wave = threadIdx.x >> 6;
    const int lane = threadIdx.x & 63;
    const int b = blockIdx.x * WAVES_PER_BLOCK + wave;
    if (b >= B) return;

    const int sub = lane >> 4;   // 0..3: which row this lane helps load
    const int l16 = lane & 15;   // 0..15: which float4 of the row

    const int start = offsets[b];
    const int end   = (b + 1 < B) ? offsets[b + 1] : N;
    const int n     = end - start;

    const int user = user_ids[b];
    const int item = item_ids[b];

    // item-embedding fragment for this lane's 4 columns (broadcast across subs)
    const float4 i4 = ((const float4*)(item_emb + (size_t)item * 64))[l16];

    float4 acc = make_float4(0.f, 0.f, 0.f, 0.f);

    // branchless deep-batched gather: DEPTH rows per sub-group per pass.
    // Invalid slots read a valid dummy (row at flat_implicit[start]) and are
    // masked out of the accumulate -> all loads issue unconditionally.
    for (int j = start + sub; j < end; j += 4 * DEPTH) {
        int idxs[DEPTH];
        #pragma unroll
        for (int i = 0; i < DEPTH; ++i) {
            const int a = j + 4 * i;
            idxs[i] = flat_implicit[(a < end) ? a : start];
        }
        float4 vals[DEPTH];
        #pragma unroll
        for (int i = 0; i < DEPTH; ++i) {
            vals[i] = ((const float4*)(imp_emb + (size_t)idxs[i] * 64))[l16];
        }
        #pragma unroll
        for (int i = 0; i < DEPTH; ++i) {
            if (j + 4 * i < end) {
                acc.x += vals[i].x; acc.y += vals[i].y;
                acc.z += vals[i].z; acc.w += vals[i].w;
            }
        }
    }

    // partial of summed·i (reduce over all 64 lanes: subs × columns)
    float ds = acc.x * i4.x + acc.y * i4.y + acc.z * i4.z + acc.w * i4.w;

    // partial of u·i: one column per lane
    const float u_c = user_emb[(size_t)user * 64 + lane];
    const float i_c = item_emb[(size_t)item * 64 + lane];
    float dui = u_c * i_c;

    // wave-wide butterfly reduction of both scalars
    #pragma unroll
    for (int off = 32; off >= 1; off >>= 1) {
        ds  += __shfl_xor(ds,  off, 64);
        dui += __shfl_xor(dui, off, 64);
    }

    if (lane == 0) {
        const float norm = (n > 0) ? sqrtf((float)n) : 1.0f;
        out[b] = dui + ds / norm + user_bias[user] + item_bias[item]
               + global_bias[0];
    }
}

extern "C" void kernel_launch(void* const* d_in, const int* in_sizes, int n_in,
                              void* d_out, int out_size, void* d_ws, size_t ws_size,
                              hipStream_t stream) {
    const int*   user_ids      = (const int*)  d_in[0];
    const int*   item_ids      = (const int*)  d_in[1];
    const int*   offsets       = (const int*)  d_in[2];
    const int*   flat_implicit = (const int*)  d_in[3];
    const float* user_emb      = (const float*)d_in[4];
    const float* item_emb      = (const float*)d_in[5];
    const float* imp_emb       = (const float*)d_in[6];
    const float* user_bias     = (const float*)d_in[7];
    const float* item_bias     = (const float*)d_in[8];
    const float* global_bias   = (const float*)d_in[9];
    float* out = (float*)d_out;

    const int B = in_sizes[0];
    const int N = in_sizes[3];

    const int grid = (B + WAVES_PER_BLOCK - 1) / WAVES_PER_BLOCK;
    svdpp_kernel<<<grid, WAVES_PER_BLOCK * 64, 0, stream>>>(
        user_ids, item_ids, offsets, flat_implicit,
        user_emb, item_emb, imp_emb,
        user_bias, item_bias, global_bias,
        out, B, N);
}

// Round 5
// 141.764 us; speedup vs baseline: 1.2660x; 1.0121x over previous
//
#include <hip/hip_runtime.h>
#include <math.h>

// SVD++ scoring, R4: forced 16-deep gather batches.
// One 64-lane wave per batch element b. sub = lane>>4 (row group),
// l16 = lane&15 (float4 within the 256B row).
// Per 64-row super-iteration: ONE coalesced load of 64 indices
// (flat_implicit[super+lane]) -> __shfl distribution -> 16 explicit named
// float4 gathers (16KB in flight per wave) -> masked accumulate.
// __launch_bounds__(256,1) lifts the VGPR cap so the compiler cannot
// strip-mine the batch (R3's arrays got squeezed to VGPR=56).
// dot(u + summed/norm, i) = u·i + (summed·i)/norm -> scalar wave reductions.

#define WAVES_PER_BLOCK 4

#define LOADIDX(d) const int idx##d = __shfl(my_idx, 4*(d) + sub, 64);
#define LOADVAL(d) const float4 v##d = impv[(size_t)idx##d * 16 + l16];
#define ACCUM(d)                                                         \
    if (super + 4*(d) + sub < end) {                                     \
        acc.x += v##d.x; acc.y += v##d.y;                                \
        acc.z += v##d.z; acc.w += v##d.w;                                \
    }

__global__ __launch_bounds__(256, 1) void svdpp_kernel(
    const int* __restrict__ user_ids,
    const int* __restrict__ item_ids,
    const int* __restrict__ offsets,
    const int* __restrict__ flat_implicit,
    const float* __restrict__ user_emb,
    const float* __restrict__ item_emb,
    const float* __restrict__ imp_emb,
    const float* __restrict__ user_bias,
    const float* __restrict__ item_bias,
    const float* __restrict__ global_bias,
    float* __restrict__ out,
    int B, int N)
{
    const int wave = threadIdx.x >> 6;
    const int lane = threadIdx.x & 63;
    const int b = blockIdx.x * WAVES_PER_BLOCK + wave;
    if (b >= B) return;

    const int sub = lane >> 4;   // 0..3: which row this lane helps load
    const int l16 = lane & 15;   // 0..15: which float4 of the row

    const int start = offsets[b];
    const int end   = (b + 1 < B) ? offsets[b + 1] : N;
    const int n     = end - start;

    const int user = user_ids[b];
    const int item = item_ids[b];

    // item-embedding fragment for this lane's 4 columns (broadcast across subs)
    const float4 i4 = ((const float4*)(item_emb + (size_t)item * 64))[l16];

    const float4* impv = (const float4*)imp_emb;
    float4 acc = make_float4(0.f, 0.f, 0.f, 0.f);

    // 64 rows per super-iteration; sub-group `sub` handles rows
    // super + 4*d + sub, d = 0..15. Out-of-range slots read a safe index
    // (flat_implicit[start]) and are masked out of the accumulate, so all
    // 16 gathers issue unconditionally.
    for (int super = start; super < end; super += 64) {
        const int a = super + lane;
        const int my_idx = flat_implicit[(a < end) ? a : start];

        LOADIDX(0)  LOADIDX(1)  LOADIDX(2)  LOADIDX(3)
        LOADIDX(4)  LOADIDX(5)  LOADIDX(6)  LOADIDX(7)
        LOADIDX(8)  LOADIDX(9)  LOADIDX(10) LOADIDX(11)
        LOADIDX(12) LOADIDX(13) LOADIDX(14) LOADIDX(15)

        LOADVAL(0)  LOADVAL(1)  LOADVAL(2)  LOADVAL(3)
        LOADVAL(4)  LOADVAL(5)  LOADVAL(6)  LOADVAL(7)
        LOADVAL(8)  LOADVAL(9)  LOADVAL(10) LOADVAL(11)
        LOADVAL(12) LOADVAL(13) LOADVAL(14) LOADVAL(15)

        ACCUM(0)  ACCUM(1)  ACCUM(2)  ACCUM(3)
        ACCUM(4)  ACCUM(5)  ACCUM(6)  ACCUM(7)
        ACCUM(8)  ACCUM(9)  ACCUM(10) ACCUM(11)
        ACCUM(12) ACCUM(13) ACCUM(14) ACCUM(15)
    }

    // partial of summed·i (reduce over all 64 lanes: subs × columns)
    float ds = acc.x * i4.x + acc.y * i4.y + acc.z * i4.z + acc.w * i4.w;

    // partial of u·i: one column per lane
    const float u_c = user_emb[(size_t)user * 64 + lane];
    const float i_c = item_emb[(size_t)item * 64 + lane];
    float dui = u_c * i_c;

    // wave-wide butterfly reduction of both scalars
    #pragma unroll
    for (int off = 32; off >= 1; off >>= 1) {
        ds  += __shfl_xor(ds,  off, 64);
        dui += __shfl_xor(dui, off, 64);
    }

    if (lane == 0) {
        const float norm = (n > 0) ? sqrtf((float)n) : 1.0f;
        out[b] = dui + ds / norm + user_bias[user] + item_bias[item]
               + global_bias[0];
    }
}

extern "C" void kernel_launch(void* const* d_in, const int* in_sizes, int n_in,
                              void* d_out, int out_size, void* d_ws, size_t ws_size,
                              hipStream_t stream) {
    const int*   user_ids      = (const int*)  d_in[0];
    const int*   item_ids      = (const int*)  d_in[1];
    const int*   offsets       = (const int*)  d_in[2];
    const int*   flat_implicit = (const int*)  d_in[3];
    const float* user_emb      = (const float*)d_in[4];
    const float* item_emb      = (const float*)d_in[5];
    const float* imp_emb       = (const float*)d_in[6];
    const float* user_bias     = (const float*)d_in[7];
    const float* item_bias     = (const float*)d_in[8];
    const float* global_bias   = (const float*)d_in[9];
    float* out = (float*)d_out;

    const int B = in_sizes[0];
    const int N = in_sizes[3];

    const int grid = (B + WAVES_PER_BLOCK - 1) / WAVES_PER_BLOCK;
    svdpp_kernel<<<grid, WAVES_PER_BLOCK * 64, 0, stream>>>(
        user_ids, item_ids, offsets, flat_implicit,
        user_emb, item_emb, imp_emb,
        user_bias, item_bias, global_bias,
        out, B, N);
}